// Round 1
// baseline (1084.279 us; speedup 1.0000x reference)
//
#include <hip/hip_runtime.h>

// R8ConvF: out[b,o,d,h,w] = sum_{c,k} w[o,c,k] * x[b,c,h+(k-1)dy_d, w+(k-1)dx_d]
// Factorization: Y_k[o,p] = sum_c W_k[o,c] x[c,p]  (3 GEMMs, bf16 MFMA)
//                out[d,p] = Y1[p] + Y0[p-delta_d] + Y2[p+delta_d]
// B=16 C=128 H=W=112 O=128 K=3, DIRS = 8 compass directions (dy,dx).

#define Bn 16
#define Cn 128
#define On 128
#define Hn 112
#define Wn 112
#define HW 12544        // 112*112
#define PBLK 128        // positions per GEMM workgroup (98 blocks per batch)
#define LDP 130         // padded p-dim in LDS (bank spread for strided reads)

typedef short short8 __attribute__((ext_vector_type(8)));
typedef float floatx4 __attribute__((ext_vector_type(4)));

__device__ __forceinline__ unsigned short f2bf(float f) {
    unsigned u = __float_as_uint(f);
    u += 0x7FFFu + ((u >> 16) & 1u);   // round-to-nearest-even
    return (unsigned short)(u >> 16);
}
__device__ __forceinline__ float bf2f(unsigned short h) {
    return __uint_as_float(((unsigned)h) << 16);
}

// ---- prep: weight fp32 [O][C][3] -> wb bf16 [3][O][C] ----------------------
__global__ __launch_bounds__(256) void prep_w(const float* __restrict__ w,
                                              unsigned short* __restrict__ wb) {
    int i = blockIdx.x * 256 + threadIdx.x;     // exactly 3*128*128 = 49152
    int k = i >> 14;            // /16384
    int r = i & 16383;          // o*128+c
    int o = r >> 7, c = r & 127;
    wb[i] = f2bf(w[(o * Cn + c) * 3 + k]);
}

// ---- kernel 1: Y[k][bl][o][p] (bf16) = W_k (bf16) @ x (bf16) via MFMA ------
// grid: (98, cnb). block 256 = 4 waves. Wave wv owns o-rows [32wv,32wv+32) for
// all 3 taps: 6 M-tiles of 16. K = C = 128 = 4 MFMA steps of 32.
__global__ __launch_bounds__(256) void k1_gemm(const float* __restrict__ x,
                                               const unsigned short* __restrict__ wb,
                                               unsigned short* __restrict__ yws,
                                               int b0, int yB) {
    __shared__ unsigned short xs[Cn * LDP];     // bf16 x-tile [c][p], 33.3 KB
    const int t = threadIdx.x;
    const int wv = t >> 6, lane = t & 63;
    const int n16 = lane & 15, q = lane >> 4;   // fragment coords
    const int bl = blockIdx.y;
    const int b = b0 + bl;
    const int pb = blockIdx.x * PBLK;

    // stage x[b, :, pb..pb+127] -> LDS bf16 (coalesced float4 reads)
    {
        const float4* xg = (const float4*)x;
        size_t xbase = (size_t)(b * Cn) * (HW / 4) + (size_t)blockIdx.x * (PBLK / 4);
        #pragma unroll
        for (int i = 0; i < 16; ++i) {
            int idx = i * 256 + t;              // 0..4095
            int c = idx >> 5, p4 = (idx & 31) * 4;
            float4 v = xg[xbase + (size_t)c * (HW / 4) + (idx & 31)];
            int la = c * LDP + p4;
            xs[la + 0] = f2bf(v.x); xs[la + 1] = f2bf(v.y);
            xs[la + 2] = f2bf(v.z); xs[la + 3] = f2bf(v.w);
        }
    }

    // A fragments: lane holds W_kk[o = ot*16 + n16][c = kc*32 + q*8 + j]
    short8 af[3][2][4];
    #pragma unroll
    for (int kk = 0; kk < 3; ++kk)
        #pragma unroll
        for (int oi = 0; oi < 2; ++oi) {
            int o = wv * 32 + oi * 16 + n16;
            #pragma unroll
            for (int kc = 0; kc < 4; ++kc)
                af[kk][oi][kc] = *(const short8*)(wb + ((kk * On + o) * Cn + kc * 32 + q * 8));
        }
    __syncthreads();

    for (int nt = 0; nt < PBLK / 16; ++nt) {
        int p0 = nt * 16;
        // B fragments: lane holds x[c = kc*32 + q*8 + j][p = p0 + n16]
        short8 bf[4];
        #pragma unroll
        for (int kc = 0; kc < 4; ++kc) {
            int cb = kc * 32 + q * 8;
            short8 v;
            #pragma unroll
            for (int j = 0; j < 8; ++j) v[j] = (short)xs[(cb + j) * LDP + p0 + n16];
            bf[kc] = v;
        }
        #pragma unroll
        for (int kk = 0; kk < 3; ++kk)
            #pragma unroll
            for (int oi = 0; oi < 2; ++oi) {
                floatx4 acc = {0.f, 0.f, 0.f, 0.f};
                #pragma unroll
                for (int kc = 0; kc < 4; ++kc)
                    acc = __builtin_amdgcn_mfma_f32_16x16x32_bf16(af[kk][oi][kc], bf[kc], acc, 0, 0, 0);
                // D layout: row = q*4 + r, col = n16
                #pragma unroll
                for (int r = 0; r < 4; ++r) {
                    int orow = wv * 32 + oi * 16 + q * 4 + r;
                    yws[((size_t)(kk * yB + bl) * On + orow) * HW + pb + p0 + n16] = f2bf(acc[r]);
                }
            }
    }
}

// ---- kernel 2: combine. grid (4 htiles, O, cnb), block 448 (= 7 waves) -----
// Each WG: (b,o,h-tile of 32 rows). Stage 3 halo'd Y planes (34 x 128-pad) in
// LDS; each thread emits one 8-wide w-group for all 8 directions.
#define LROW 128        // padded LDS row: col j = w+8; j=7 is w=-1, j=120 is w=112
__global__ __launch_bounds__(448) void k2_combine(const unsigned short* __restrict__ yws,
                                                  float* __restrict__ out,
                                                  int b0, int yB) {
    __shared__ unsigned short yt[3 * 34 * LROW];    // 26.1 KB
    const int t = threadIdx.x;
    const int ht = blockIdx.x;
    const int o = blockIdx.y;
    const int bl = blockIdx.z;
    const int b = b0 + bl;
    const int h0 = ht * 32;

    // staging: 3 planes x 34 rows x (14 vec-segments + 1 border job)
    for (int i = t; i < 3 * 34 * 15; i += 448) {
        int rj = i / 15, seg = i - rj * 15;
        int k = rj / 34, hr = rj - k * 34;
        int h = h0 - 1 + hr;
        if (seg < 14) {
            short8 v = {0, 0, 0, 0, 0, 0, 0, 0};
            if (h >= 0 && h < Hn)
                v = *(const short8*)(yws + ((size_t)(k * yB + bl) * On + o) * HW + h * Wn + seg * 8);
            *(short8*)(yt + (k * 34 + hr) * LROW + 8 + seg * 8) = v;
        } else {
            yt[(k * 34 + hr) * LROW + 7] = 0;      // w = -1
            yt[(k * 34 + hr) * LROW + 120] = 0;    // w = 112
        }
    }
    __syncthreads();

    int hr = t / 14, g = t - hr * 14;
    int h = h0 + hr;
    if (h >= Hn) return;
    int lr = hr + 1;            // center row in tile coords
    int jb = 8 + g * 8;         // LDS col of w = g*8

    float y0[3][10], y2[3][10], y1[8];
    #pragma unroll
    for (int r = 0; r < 3; ++r)
        #pragma unroll
        for (int j = 0; j < 10; ++j) {
            y0[r][j] = bf2f(yt[(0 * 34 + lr - 1 + r) * LROW + jb - 1 + j]);
            y2[r][j] = bf2f(yt[(2 * 34 + lr - 1 + r) * LROW + jb - 1 + j]);
        }
    #pragma unroll
    for (int j = 0; j < 8; ++j) y1[j] = bf2f(yt[(1 * 34 + lr) * LROW + jb + j]);

    const int DY[8] = {0, 1, 1, 1, 0, -1, -1, -1};
    const int DX[8] = {1, 1, 0, -1, -1, -1, 0, 1};
    size_t obase = ((size_t)(b * On + o) * 8) * HW + (size_t)h * Wn + g * 8;
    #pragma unroll
    for (int d = 0; d < 8; ++d) {
        int dy = DY[d], dx = DX[d];
        float vv[8];
        #pragma unroll
        for (int i = 0; i < 8; ++i)
            vv[i] = y1[i] + y0[1 - dy][i + 1 - dx] + y2[1 + dy][i + 1 + dx];
        float4* po = (float4*)(out + obase + (size_t)d * HW);
        po[0] = make_float4(vv[0], vv[1], vv[2], vv[3]);
        po[1] = make_float4(vv[4], vv[5], vv[6], vv[7]);
    }
}

// ---- naive fallback (only if workspace < 1 batch of Y) ---------------------
__global__ __launch_bounds__(256) void k_naive(const float* __restrict__ x,
                                               const float* __restrict__ w,
                                               float* __restrict__ out) {
    const int DY[8] = {0, 1, 1, 1, 0, -1, -1, -1};
    const int DX[8] = {1, 1, 0, -1, -1, -1, 0, 1};
    size_t idx = (size_t)blockIdx.x * 256 + threadIdx.x;
    if (idx >= (size_t)Bn * On * 8 * HW) return;
    int ww = idx % Wn; size_t r = idx / Wn;
    int hh = r % Hn; r /= Hn;
    int d = r % 8; r /= 8;
    int o = r % On; int b = (int)(r / On);
    float s = 0.f;
    for (int c = 0; c < Cn; ++c)
        for (int k = 0; k < 3; ++k) {
            int h2 = hh + (k - 1) * DY[d], w2 = ww + (k - 1) * DX[d];
            if (h2 >= 0 && h2 < Hn && w2 >= 0 && w2 < Wn)
                s += w[(o * Cn + c) * 3 + k] * x[(size_t)(b * Cn + c) * HW + h2 * Wn + w2];
        }
    out[idx] = s;
}

extern "C" void kernel_launch(void* const* d_in, const int* in_sizes, int n_in,
                              void* d_out, int out_size, void* d_ws, size_t ws_size,
                              hipStream_t stream) {
    const float* x = (const float*)d_in[0];
    const float* w = (const float*)d_in[1];
    float* out = (float*)d_out;

    unsigned short* wb = (unsigned short*)d_ws;                       // 96 KB
    unsigned short* yws = (unsigned short*)((char*)d_ws + 98304);
    const size_t perB = (size_t)3 * On * HW * 2;                      // 9.63 MB / batch
    size_t avail = ws_size > 98304 ? ws_size - 98304 : 0;
    int nb = (int)(avail / perB);
    if (nb > Bn) nb = Bn;

    if (nb < 1) {   // workspace too small for even one batch: slow-but-correct
        size_t total = (size_t)Bn * On * 8 * HW;
        k_naive<<<dim3((unsigned)((total + 255) / 256)), 256, 0, stream>>>(x, w, out);
        return;
    }

    prep_w<<<192, 256, 0, stream>>>(w, wb);
    for (int b0 = 0; b0 < Bn; b0 += nb) {
        int cnb = (Bn - b0 < nb) ? (Bn - b0) : nb;
        k1_gemm<<<dim3(HW / PBLK, cnb), 256, 0, stream>>>(x, wb, yws, b0, nb);
        k2_combine<<<dim3(4, On, cnb), 448, 0, stream>>>(yws, out, b0, nb);
    }
}